// Round 12
// baseline (1020.903 us; speedup 1.0000x reference)
//
#include <hip/hip_runtime.h>
#include <cstdint>
#include <cstddef>

#define NPOINT 1024
#define NSAMPLE 32
#define BATCH 8
#define NPTS 4096
#define DFEAT 64
#define CIN 67
#define C1 64
#define C2 64
#define C3 128
#define BN_EPS 1e-5f

// ---------------------------------------------------------------------------
// FPS (blocks 0..7) + points-transpose (blocks 8..519) in ONE dispatch.
// FPS body = r8 champion (644 us): LDS-resident points -> register scan
// arrays, scalar bit-exact distance math, DPP value-only wave-max,
// ballot+ctz+readlane index recovery, u64-packed per-wave key in
// double-buffered LDS, single barrier per step, serial-8 key reduce,
// register-latched output. Transpose blocks run on idle CUs.
// NOTE (measured): v_pk_*_f32 is NOT double-rate on gfx950 (r10: 722 vs 644;
// r11 mlp pk regression) — keep all math scalar.
// ---------------------------------------------------------------------------
__device__ __forceinline__ float wave64_max_bcast(float v) {
    // values must be >= 0 (bound_ctrl zero-fill loses). Result via lane 63.
    int x;
    x = __builtin_amdgcn_update_dpp(0, __float_as_int(v), 0x111, 0xf, 0xf, true);
    v = fmaxf(v, __int_as_float(x));  // row_shr:1
    x = __builtin_amdgcn_update_dpp(0, __float_as_int(v), 0x112, 0xf, 0xf, true);
    v = fmaxf(v, __int_as_float(x));  // row_shr:2
    x = __builtin_amdgcn_update_dpp(0, __float_as_int(v), 0x114, 0xf, 0xf, true);
    v = fmaxf(v, __int_as_float(x));  // row_shr:4
    x = __builtin_amdgcn_update_dpp(0, __float_as_int(v), 0x118, 0xf, 0xf, true);
    v = fmaxf(v, __int_as_float(x));  // row_shr:8
    x = __builtin_amdgcn_update_dpp(0, __float_as_int(v), 0x142, 0xf, 0xf, true);
    v = fmaxf(v, __int_as_float(x));  // row_bcast:15
    x = __builtin_amdgcn_update_dpp(0, __float_as_int(v), 0x143, 0xf, 0xf, true);
    v = fmaxf(v, __int_as_float(x));  // row_bcast:31
    return __int_as_float(__builtin_amdgcn_readlane(__float_as_int(v), 63));
}

__global__ __launch_bounds__(512) void fps_transpose_kernel(
    const float* __restrict__ xyz, float* __restrict__ dout,
    const float* __restrict__ pts, float* __restrict__ ptsT) {
    __shared__ __align__(16) float smem[3 * NPTS + 32];

    if (blockIdx.x >= BATCH) {
        // ---------------- transpose block: one 64-point tile -------------
        const int tb = blockIdx.x - BATCH;
        float (*tile)[65] = (float(*)[65])smem;
        const int b = tb / (NPTS / 64);
        const int n0 = (tb % (NPTS / 64)) * 64;
        const int t = threadIdx.x;
        const int nl = t & 63, cq = t >> 6;  // cq in 0..7
        const float* pb = pts + (size_t)b * DFEAT * NPTS;
#pragma unroll
        for (int i = 0; i < 8; ++i) {
            int c = i * 8 + cq;
            tile[c][nl] = pb[(size_t)c * NPTS + n0 + nl];
        }
        __syncthreads();
        float* ob = ptsT + (size_t)b * NPTS * DFEAT;
        const int cl = t & 63, nq = t >> 6;
#pragma unroll
        for (int i = 0; i < 8; ++i) {
            int n = i * 8 + nq;
            ob[(size_t)(n0 + n) * DFEAT + cl] = tile[cl][n];
        }
        return;
    }

    // -------------------------- FPS block (r8 body) ----------------------
    const int b = blockIdx.x;
    const float* xb = xyz + (size_t)b * 3 * NPTS;
    float* ox = dout + (size_t)b * 3 * NPOINT;

    float* sx = smem;
    float* sy = smem + NPTS;
    float* sz = smem + 2 * NPTS;
    unsigned long long (*redk)[8] = (unsigned long long(*)[8])(smem + 3 * NPTS);

    const int t = threadIdx.x;
    const int wv = t >> 6;
    for (int j = t; j < NPTS; j += 512) {
        sx[j] = xb[j];
        sy[j] = xb[NPTS + j];
        sz[j] = xb[2 * NPTS + j];
    }
    __syncthreads();

    constexpr int PT = NPTS / 512;  // 8 points per thread, contiguous
    float px[PT], py[PT], pz[PT], dist[PT];
    const int base = t * PT;
#pragma unroll
    for (int u = 0; u < PT; ++u) {
        px[u] = sx[base + u];
        py[u] = sy[base + u];
        pz[u] = sz[base + u];
        dist[u] = 1e10f;
    }

    int last = 0;
    float o0x = 0.f, o0y = 0.f, o0z = 0.f;  // centroid index t
    float o1x = 0.f, o1y = 0.f, o1z = 0.f;  // centroid index t + 512

    for (int s = 1; s < NPOINT; ++s) {
        const float cx = sx[last], cy = sy[last], cz = sz[last];
        // latch centroid (s-1): its coords are exactly (cx,cy,cz)
        if (s - 1 == t)       { o0x = cx; o0y = cy; o0z = cz; }
        if (s - 1 == t + 512) { o1x = cx; o1y = cy; o1z = cz; }

        float bv = 0.0f;
#pragma unroll
        for (int u = 0; u < PT; ++u) {
            float dx = __fsub_rn(px[u], cx);
            float dy = __fsub_rn(py[u], cy);
            float dz = __fsub_rn(pz[u], cz);
            float d = __fadd_rn(__fadd_rn(__fmul_rn(dx, dx), __fmul_rn(dy, dy)),
                                __fmul_rn(dz, dz));
            float nd = fminf(dist[u], d);
            dist[u] = nd;
            bv = fmaxf(bv, nd);
        }
        // wave-level max (DPP, VALU-pipe) then recover first matching index
        const float wmax = wave64_max_bcast(bv);
        int li = 0;
        if (bv == wmax) {
#pragma unroll
            for (int u = PT - 1; u >= 0; --u)
                if (dist[u] == wmax) li = base + u;  // descending -> smallest
        }
        const unsigned long long m = __ballot(bv == wmax);
        const int fl = __builtin_ctzll(m);  // first matching lane = smallest idx
        const int wbi = __builtin_amdgcn_readlane(li, fl);

        if ((t & 63) == 0) {
            redk[s & 1][wv] =
                ((unsigned long long)__float_as_uint(wmax) << 32) |
                (unsigned)(0xFFFFFFFFu - (unsigned)wbi);
        }
        __syncthreads();
        unsigned long long gk = redk[s & 1][0];
#pragma unroll
        for (int w = 1; w < 8; ++w) {
            unsigned long long k2 = redk[s & 1][w];
            if (k2 > gk) gk = k2;
        }
        last = (int)(0xFFFFFFFFu - (unsigned)(gk & 0xFFFFFFFFull));
        // no in-loop store, no second barrier (redk double-buffered)
    }

    // centroid 1023 (selected in the final iteration, never re-read in-loop)
    {
        const float cx = sx[last], cy = sy[last], cz = sz[last];
        if (t == 511) { o1x = cx; o1y = cy; o1z = cz; }  // 1023 == 511 + 512
    }

    // coalesced final writes (1024 centroids, 2 per thread)
    ox[t] = o0x;
    ox[NPOINT + t] = o0y;
    ox[2 * NPOINT + t] = o0z;
    ox[512 + t] = o1x;
    ox[NPOINT + 512 + t] = o1y;
    ox[2 * NPOINT + 512 + t] = o1z;
}

// ---------------------------------------------------------------------------
// Ball query: one wave per query point. First 32 ascending indices with
// d2 <= r2, padded with the first. Bit-exact d2. Parallel emission via
// prefix popcount.
// ---------------------------------------------------------------------------
__global__ __launch_bounds__(256) void ballquery_kernel(const float* __restrict__ xyz,
                                                        const float* __restrict__ dout,
                                                        int* __restrict__ idx) {
    const int wv = threadIdx.x >> 6, lane = threadIdx.x & 63;
    const int sg = blockIdx.x * 4 + wv;  // b*NPOINT + s
    const int b = sg / NPOINT, s = sg % NPOINT;
    const float* xb = xyz + (size_t)b * 3 * NPTS;
    const float* nx = dout + (size_t)b * 3 * NPOINT;
    const float cx = nx[s], cy = nx[NPOINT + s], cz = nx[2 * NPOINT + s];
    int* ob = idx + (size_t)sg * NSAMPLE;
    const float r2 = 0.04f;  // f32(0.2*0.2)
    const unsigned long long lmask_lt = ((unsigned long long)1 << lane) - 1;

    int cnt = 0;
    int first = -1;
    for (int tch = 0; tch < NPTS / 64 && cnt < NSAMPLE; ++tch) {
        const int j = tch * 64 + lane;
        float dx = __fsub_rn(cx, xb[j]);
        float dy = __fsub_rn(cy, xb[NPTS + j]);
        float dz = __fsub_rn(cz, xb[2 * NPTS + j]);
        float d2 = __fadd_rn(__fadd_rn(__fmul_rn(dx, dx), __fmul_rn(dy, dy)),
                             __fmul_rn(dz, dz));
        const bool in = (d2 <= r2);
        const unsigned long long mask = __ballot(in);
        if (first < 0 && mask)
            first = tch * 64 + __builtin_ctzll(mask);
        if (in) {
            const int pos = cnt + __builtin_popcountll(mask & lmask_lt);
            if (pos < NSAMPLE) ob[pos] = j;
        }
        cnt += __builtin_popcountll(mask);
    }
    if (lane == 0) {
        for (int r = cnt; r < NSAMPLE; ++r) ob[r] = first;
    }
}

// ---------------------------------------------------------------------------
// Fused group + 3x conv-BN-ReLU + max over nsample.
// ONE WAVE per block (64 thr = 2 s x 32 k): the ylds activation bounce is
// thread-private (thread t only touches column t), so with a single wave NO
// barriers are needed at all — the compiler's lgkmcnt waits cover the LDS
// round-trip. 16KB LDS -> ~10 blocks/CU (vs 8 waves/CU before).
// Scalar math identical to the r8 champion (bitwise-same outputs).
// ---------------------------------------------------------------------------
template <int TRANSPOSED>
__global__ __launch_bounds__(64) void mlp_kernel(
    const float* __restrict__ xyz, const float* __restrict__ pts,
    const int* __restrict__ idx, const float* __restrict__ dnew,
    const float* __restrict__ w0, const float* __restrict__ b0,
    const float* __restrict__ g0, const float* __restrict__ bt0,
    const float* __restrict__ rm0, const float* __restrict__ rv0,
    const float* __restrict__ w1, const float* __restrict__ b1,
    const float* __restrict__ g1, const float* __restrict__ bt1,
    const float* __restrict__ rm1, const float* __restrict__ rv1,
    const float* __restrict__ w2, const float* __restrict__ b2,
    const float* __restrict__ g2, const float* __restrict__ bt2,
    const float* __restrict__ rm2, const float* __restrict__ rv2,
    float* __restrict__ outf) {
    __shared__ float ylds[64][64];  // 16 KB, column t private to thread t
    const int t = threadIdx.x;       // 0..63
    const int k = t & 31, sl = t >> 5;
    const int sg = blockIdx.x * 2 + sl;   // b*NPOINT + s
    const int b = sg >> 10;               // / NPOINT
    const int s = sg & (NPOINT - 1);
    const int p = idx[(size_t)sg * NSAMPLE + k];

    const float* xb = xyz + (size_t)b * 3 * NPTS;
    const float* nx = dnew + (size_t)b * 3 * NPOINT;

    float x[CIN];
    x[0] = xb[p] - nx[s];
    x[1] = xb[NPTS + p] - nx[NPOINT + s];
    x[2] = xb[2 * NPTS + p] - nx[2 * NPOINT + s];
    if (TRANSPOSED) {
        const float* pb = pts + ((size_t)b * NPTS + p) * DFEAT;
#pragma unroll
        for (int c = 0; c < DFEAT; ++c) x[3 + c] = pb[c];
    } else {
        const float* pb = pts + (size_t)b * DFEAT * NPTS + p;
#pragma unroll
        for (int c = 0; c < DFEAT; ++c) x[3 + c] = pb[(size_t)c * NPTS];
    }

    // layer 1: 67 -> 64
    for (int o = 0; o < C1; ++o) {
        const float* wr = w0 + o * CIN;
        float a0 = 0.f, a1 = 0.f, a2 = 0.f, a3 = 0.f;
#pragma unroll
        for (int c = 0; c < 64; c += 4) {
            a0 = fmaf(wr[c], x[c], a0);
            a1 = fmaf(wr[c + 1], x[c + 1], a1);
            a2 = fmaf(wr[c + 2], x[c + 2], a2);
            a3 = fmaf(wr[c + 3], x[c + 3], a3);
        }
        a0 = fmaf(wr[64], x[64], a0);
        a1 = fmaf(wr[65], x[65], a1);
        a2 = fmaf(wr[66], x[66], a2);
        float acc = (a0 + a1) + (a2 + a3);
        float sc = g0[o] * rsqrtf(rv0[o] + BN_EPS);
        float y = fmaf(sc, acc + b0[o] - rm0[o], bt0[o]);
        ylds[o][t] = fmaxf(y, 0.f);
    }
    float x1[C1];
#pragma unroll
    for (int c = 0; c < C1; ++c) x1[c] = ylds[c][t];

    // layer 2: 64 -> 64 (in-place ylds reuse: column t is thread-private)
    for (int o = 0; o < C2; ++o) {
        const float* wr = w1 + o * C1;
        float a0 = 0.f, a1 = 0.f, a2 = 0.f, a3 = 0.f;
#pragma unroll
        for (int c = 0; c < C1; c += 4) {
            a0 = fmaf(wr[c], x1[c], a0);
            a1 = fmaf(wr[c + 1], x1[c + 1], a1);
            a2 = fmaf(wr[c + 2], x1[c + 2], a2);
            a3 = fmaf(wr[c + 3], x1[c + 3], a3);
        }
        float acc = (a0 + a1) + (a2 + a3);
        float sc = g1[o] * rsqrtf(rv1[o] + BN_EPS);
        float y = fmaf(sc, acc + b1[o] - rm1[o], bt1[o]);
        ylds[o][t] = fmaxf(y, 0.f);
    }
    float x2[C2];
#pragma unroll
    for (int c = 0; c < C2; ++c) x2[c] = ylds[c][t];

    // layer 3: 64 -> 128, then max over k (32 lanes sharing s)
    float* ob = outf + (size_t)b * C3 * NPOINT;
    for (int o = 0; o < C3; ++o) {
        const float* wr = w2 + o * C2;
        float a0 = 0.f, a1 = 0.f, a2 = 0.f, a3 = 0.f;
#pragma unroll
        for (int c = 0; c < C2; c += 4) {
            a0 = fmaf(wr[c], x2[c], a0);
            a1 = fmaf(wr[c + 1], x2[c + 1], a1);
            a2 = fmaf(wr[c + 2], x2[c + 2], a2);
            a3 = fmaf(wr[c + 3], x2[c + 3], a3);
        }
        float acc = (a0 + a1) + (a2 + a3);
        float sc = g2[o] * rsqrtf(rv2[o] + BN_EPS);
        float y = fmaf(sc, acc + b2[o] - rm2[o], bt2[o]);
        float v = fmaxf(y, 0.f);
#pragma unroll
        for (int m = 16; m >= 1; m >>= 1) v = fmaxf(v, __shfl_xor(v, m, 32));
        if (k == 0) ob[(size_t)o * NPOINT + s] = v;
    }
}

// ---------------------------------------------------------------------------
extern "C" void kernel_launch(void* const* d_in, const int* in_sizes, int n_in,
                              void* d_out, int out_size, void* d_ws, size_t ws_size,
                              hipStream_t stream) {
    const float* xyz = (const float*)d_in[0];
    const float* pts = (const float*)d_in[1];
    const float* w0 = (const float*)d_in[2];
    const float* b0 = (const float*)d_in[3];
    const float* g0 = (const float*)d_in[4];
    const float* bt0 = (const float*)d_in[5];
    const float* rm0 = (const float*)d_in[6];
    const float* rv0 = (const float*)d_in[7];
    const float* w1 = (const float*)d_in[8];
    const float* b1 = (const float*)d_in[9];
    const float* g1 = (const float*)d_in[10];
    const float* bt1 = (const float*)d_in[11];
    const float* rm1 = (const float*)d_in[12];
    const float* rv1 = (const float*)d_in[13];
    const float* w2 = (const float*)d_in[14];
    const float* b2 = (const float*)d_in[15];
    const float* g2 = (const float*)d_in[16];
    const float* bt2 = (const float*)d_in[17];
    const float* rm2 = (const float*)d_in[18];
    const float* rv2 = (const float*)d_in[19];

    float* out = (float*)d_out;
    float* outf = out + (size_t)BATCH * 3 * NPOINT;

    const size_t idx_bytes = (size_t)BATCH * NPOINT * NSAMPLE * sizeof(int);  // 1 MB
    const size_t idx_pad = (idx_bytes + 255) & ~(size_t)255;
    const size_t ptsT_bytes = (size_t)BATCH * NPTS * DFEAT * sizeof(float);   // 8 MB
    int* idx = (int*)d_ws;
    float* ptsT = (float*)((char*)d_ws + idx_pad);
    const bool useT = ws_size >= idx_pad + ptsT_bytes;

    const int ngrid = BATCH + (useT ? BATCH * (NPTS / 64) : 0);
    fps_transpose_kernel<<<ngrid, 512, 0, stream>>>(xyz, out, pts, ptsT);
    ballquery_kernel<<<BATCH * NPOINT / 4, 256, 0, stream>>>(xyz, out, idx);
    if (useT) {
        mlp_kernel<1><<<BATCH * NPOINT / 2, 64, 0, stream>>>(
            xyz, ptsT, idx, out, w0, b0, g0, bt0, rm0, rv0, w1, b1, g1, bt1, rm1,
            rv1, w2, b2, g2, bt2, rm2, rv2, outf);
    } else {
        mlp_kernel<0><<<BATCH * NPOINT / 2, 64, 0, stream>>>(
            xyz, pts, idx, out, w0, b0, g0, bt0, rm0, rv0, w1, b1, g1, bt1, rm1,
            rv1, w2, b2, g2, bt2, rm2, rv2, outf);
    }
}

// Round 13
// 926.389 us; speedup vs baseline: 1.1020x; 1.1020x over previous
//
#include <hip/hip_runtime.h>
#include <cstdint>
#include <cstddef>

#define NPOINT 1024
#define NSAMPLE 32
#define BATCH 8
#define NPTS 4096
#define DFEAT 64
#define CIN 67
#define C1 64
#define C2 64
#define C3 128
#define BN_EPS 1e-5f

// ---------------------------------------------------------------------------
// FPS: one block per batch, 512 threads (8 waves). Byte-identical to the r8
// champion (644 us): LDS-resident points -> register scan arrays, scalar
// bit-exact distance math, DPP value-only wave-max, ballot+ctz+readlane
// index recovery, u64-packed per-wave key in double-buffered LDS, single
// barrier per step, serial-8 key reduce, register-latched output.
// NOTE (measured): v_pk_*_f32 is NOT double-rate on gfx950 (r10/r11) — all
// math scalar.
// ---------------------------------------------------------------------------
__device__ __forceinline__ float wave64_max_bcast(float v) {
    // values must be >= 0 (bound_ctrl zero-fill loses). Result via lane 63.
    int x;
    x = __builtin_amdgcn_update_dpp(0, __float_as_int(v), 0x111, 0xf, 0xf, true);
    v = fmaxf(v, __int_as_float(x));  // row_shr:1
    x = __builtin_amdgcn_update_dpp(0, __float_as_int(v), 0x112, 0xf, 0xf, true);
    v = fmaxf(v, __int_as_float(x));  // row_shr:2
    x = __builtin_amdgcn_update_dpp(0, __float_as_int(v), 0x114, 0xf, 0xf, true);
    v = fmaxf(v, __int_as_float(x));  // row_shr:4
    x = __builtin_amdgcn_update_dpp(0, __float_as_int(v), 0x118, 0xf, 0xf, true);
    v = fmaxf(v, __int_as_float(x));  // row_shr:8
    x = __builtin_amdgcn_update_dpp(0, __float_as_int(v), 0x142, 0xf, 0xf, true);
    v = fmaxf(v, __int_as_float(x));  // row_bcast:15
    x = __builtin_amdgcn_update_dpp(0, __float_as_int(v), 0x143, 0xf, 0xf, true);
    v = fmaxf(v, __int_as_float(x));  // row_bcast:31
    return __int_as_float(__builtin_amdgcn_readlane(__float_as_int(v), 63));
}

// max over each 32-lane half (negatives safe: bound_ctrl=false keeps own
// value on invalid source lanes). Result valid in lanes 31 and 63.
__device__ __forceinline__ float max32_lane31(float v) {
    int iv = __float_as_int(v), x;
    x = __builtin_amdgcn_update_dpp(iv, iv, 0x111, 0xf, 0xf, false);  // shr1
    v = fmaxf(v, __int_as_float(x)); iv = __float_as_int(v);
    x = __builtin_amdgcn_update_dpp(iv, iv, 0x112, 0xf, 0xf, false);  // shr2
    v = fmaxf(v, __int_as_float(x)); iv = __float_as_int(v);
    x = __builtin_amdgcn_update_dpp(iv, iv, 0x114, 0xf, 0xf, false);  // shr4
    v = fmaxf(v, __int_as_float(x)); iv = __float_as_int(v);
    x = __builtin_amdgcn_update_dpp(iv, iv, 0x118, 0xf, 0xf, false);  // shr8
    v = fmaxf(v, __int_as_float(x)); iv = __float_as_int(v);
    x = __builtin_amdgcn_update_dpp(iv, iv, 0x142, 0xf, 0xf, false);  // bcast15
    v = fmaxf(v, __int_as_float(x));
    return v;
}

__global__ __launch_bounds__(512) void fps_kernel(const float* __restrict__ xyz,
                                                  float* __restrict__ dout) {
    const int b = blockIdx.x;
    const float* xb = xyz + (size_t)b * 3 * NPTS;
    float* ox = dout + (size_t)b * 3 * NPOINT;

    __shared__ float sx[NPTS], sy[NPTS], sz[NPTS];
    __shared__ unsigned long long redk[2][8];

    const int t = threadIdx.x;
    const int wv = t >> 6;
    for (int j = t; j < NPTS; j += 512) {
        sx[j] = xb[j];
        sy[j] = xb[NPTS + j];
        sz[j] = xb[2 * NPTS + j];
    }
    __syncthreads();

    constexpr int PT = NPTS / 512;  // 8 points per thread, contiguous
    float px[PT], py[PT], pz[PT], dist[PT];
    const int base = t * PT;
#pragma unroll
    for (int u = 0; u < PT; ++u) {
        px[u] = sx[base + u];
        py[u] = sy[base + u];
        pz[u] = sz[base + u];
        dist[u] = 1e10f;
    }

    int last = 0;
    float o0x = 0.f, o0y = 0.f, o0z = 0.f;  // centroid index t
    float o1x = 0.f, o1y = 0.f, o1z = 0.f;  // centroid index t + 512

    for (int s = 1; s < NPOINT; ++s) {
        const float cx = sx[last], cy = sy[last], cz = sz[last];
        if (s - 1 == t)       { o0x = cx; o0y = cy; o0z = cz; }
        if (s - 1 == t + 512) { o1x = cx; o1y = cy; o1z = cz; }

        float bv = 0.0f;
#pragma unroll
        for (int u = 0; u < PT; ++u) {
            float dx = __fsub_rn(px[u], cx);
            float dy = __fsub_rn(py[u], cy);
            float dz = __fsub_rn(pz[u], cz);
            float d = __fadd_rn(__fadd_rn(__fmul_rn(dx, dx), __fmul_rn(dy, dy)),
                                __fmul_rn(dz, dz));
            float nd = fminf(dist[u], d);
            dist[u] = nd;
            bv = fmaxf(bv, nd);
        }
        const float wmax = wave64_max_bcast(bv);
        int li = 0;
        if (bv == wmax) {
#pragma unroll
            for (int u = PT - 1; u >= 0; --u)
                if (dist[u] == wmax) li = base + u;  // descending -> smallest
        }
        const unsigned long long m = __ballot(bv == wmax);
        const int fl = __builtin_ctzll(m);
        const int wbi = __builtin_amdgcn_readlane(li, fl);

        if ((t & 63) == 0) {
            redk[s & 1][wv] =
                ((unsigned long long)__float_as_uint(wmax) << 32) |
                (unsigned)(0xFFFFFFFFu - (unsigned)wbi);
        }
        __syncthreads();
        unsigned long long gk = redk[s & 1][0];
#pragma unroll
        for (int w = 1; w < 8; ++w) {
            unsigned long long k2 = redk[s & 1][w];
            if (k2 > gk) gk = k2;
        }
        last = (int)(0xFFFFFFFFu - (unsigned)(gk & 0xFFFFFFFFull));
    }

    {
        const float cx = sx[last], cy = sy[last], cz = sz[last];
        if (t == 511) { o1x = cx; o1y = cy; o1z = cz; }  // 1023 == 511 + 512
    }

    ox[t] = o0x;
    ox[NPOINT + t] = o0y;
    ox[2 * NPOINT + t] = o0z;
    ox[512 + t] = o1x;
    ox[NPOINT + 512 + t] = o1y;
    ox[2 * NPOINT + 512 + t] = o1z;
}

// ---------------------------------------------------------------------------
// A[b][n][o] = sum_c W0[o][3+c] * pts[b][c][n]  — the pts-dependent part of
// layer 1, shared by all (s,k) referencing point n (avg ~8 refs/point).
// Replaces the plain transpose: same (B,N,64) contiguous-gather layout.
// ---------------------------------------------------------------------------
__global__ __launch_bounds__(256) void layer1_pts_kernel(
    const float* __restrict__ pts, const float* __restrict__ w0,
    float* __restrict__ A) {
    __shared__ float sp[64][65];  // [c][n]
    __shared__ float sw[64][65];  // [o][c]
    const int b = blockIdx.x >> 6;              // 64 n-tiles per batch
    const int n0 = (blockIdx.x & 63) * 64;
    const int t = threadIdx.x;
    const int tn = t & 63, tq = t >> 6;         // tq in 0..3
    const float* pb = pts + (size_t)b * DFEAT * NPTS;
#pragma unroll
    for (int i = 0; i < 16; ++i) {
        int c = i * 4 + tq;
        sp[c][tn] = pb[(size_t)c * NPTS + n0 + tn];
    }
#pragma unroll
    for (int i = 0; i < 16; ++i) {
        int o = i * 4 + tq;
        sw[o][tn] = w0[o * CIN + 3 + tn];
    }
    __syncthreads();

    float* An = A + ((size_t)b * NPTS + n0 + tn) * DFEAT;
#pragma unroll
    for (int i = 0; i < 16; ++i) {
        const int o = tq * 16 + i;
        float a0 = 0.f, a1 = 0.f, a2 = 0.f, a3 = 0.f;
#pragma unroll
        for (int c = 0; c < 64; c += 4) {
            a0 = fmaf(sw[o][c], sp[c][tn], a0);
            a1 = fmaf(sw[o][c + 1], sp[c + 1][tn], a1);
            a2 = fmaf(sw[o][c + 2], sp[c + 2][tn], a2);
            a3 = fmaf(sw[o][c + 3], sp[c + 3][tn], a3);
        }
        An[o] = (a0 + a1) + (a2 + a3);
    }
}

// ---------------------------------------------------------------------------
// Ball query: one wave per query point. First 32 ascending indices with
// d2 <= r2, padded with the first. Bit-exact d2. Parallel emission via
// prefix popcount.
// ---------------------------------------------------------------------------
__global__ __launch_bounds__(256) void ballquery_kernel(const float* __restrict__ xyz,
                                                        const float* __restrict__ dout,
                                                        int* __restrict__ idx) {
    const int wv = threadIdx.x >> 6, lane = threadIdx.x & 63;
    const int sg = blockIdx.x * 4 + wv;  // b*NPOINT + s
    const int b = sg / NPOINT, s = sg % NPOINT;
    const float* xb = xyz + (size_t)b * 3 * NPTS;
    const float* nx = dout + (size_t)b * 3 * NPOINT;
    const float cx = nx[s], cy = nx[NPOINT + s], cz = nx[2 * NPOINT + s];
    int* ob = idx + (size_t)sg * NSAMPLE;
    const float r2 = 0.04f;  // f32(0.2*0.2)
    const unsigned long long lmask_lt = ((unsigned long long)1 << lane) - 1;

    int cnt = 0;
    int first = -1;
    for (int tch = 0; tch < NPTS / 64 && cnt < NSAMPLE; ++tch) {
        const int j = tch * 64 + lane;
        float dx = __fsub_rn(cx, xb[j]);
        float dy = __fsub_rn(cy, xb[NPTS + j]);
        float dz = __fsub_rn(cz, xb[2 * NPTS + j]);
        float d2 = __fadd_rn(__fadd_rn(__fmul_rn(dx, dx), __fmul_rn(dy, dy)),
                             __fmul_rn(dz, dz));
        const bool in = (d2 <= r2);
        const unsigned long long mask = __ballot(in);
        if (first < 0 && mask)
            first = tch * 64 + __builtin_ctzll(mask);
        if (in) {
            const int pos = cnt + __builtin_popcountll(mask & lmask_lt);
            if (pos < NSAMPLE) ob[pos] = j;
        }
        cnt += __builtin_popcountll(mask);
    }
    if (lane == 0) {
        for (int r = cnt; r < NSAMPLE; ++r) ob[r] = first;
    }
}

// ---------------------------------------------------------------------------
// Fused group + 3x conv-BN-ReLU + max over nsample. 256 thr (8 s x 32 k).
// MODE1: layer 1 = 3 xyz FMAs + precomputed A[p] row (float4 groups, static
// sub-indexing). Layer 3: k-max via DPP (VALU pipe, no ds_bpermute), BN+ReLU
// applied AFTER the max (monotone => bitwise identical; sign-safe).
// ---------------------------------------------------------------------------
template <int MODE>
__global__ __launch_bounds__(256) void mlp_kernel(
    const float* __restrict__ xyz, const float* __restrict__ pts,
    const float* __restrict__ A, const int* __restrict__ idx,
    const float* __restrict__ dnew,
    const float* __restrict__ w0, const float* __restrict__ b0,
    const float* __restrict__ g0, const float* __restrict__ bt0,
    const float* __restrict__ rm0, const float* __restrict__ rv0,
    const float* __restrict__ w1, const float* __restrict__ b1,
    const float* __restrict__ g1, const float* __restrict__ bt1,
    const float* __restrict__ rm1, const float* __restrict__ rv1,
    const float* __restrict__ w2, const float* __restrict__ b2,
    const float* __restrict__ g2, const float* __restrict__ bt2,
    const float* __restrict__ rm2, const float* __restrict__ rv2,
    float* __restrict__ outf) {
    __shared__ float ylds[64][256];
    const int t = threadIdx.x;
    const int k = t & 31, sl = t >> 5;
    const int b = blockIdx.x >> 7;
    const int s = (blockIdx.x & 127) * 8 + sl;
    const int p = idx[((size_t)(b * NPOINT + s)) * NSAMPLE + k];

    const float* xb = xyz + (size_t)b * 3 * NPTS;
    const float* nx = dnew + (size_t)b * 3 * NPOINT;

    const float gx = xb[p] - nx[s];
    const float gy = xb[NPTS + p] - nx[NPOINT + s];
    const float gz = xb[2 * NPTS + p] - nx[2 * NPOINT + s];

    if (MODE == 1) {
        // layer 1 via precomputed A row
        const float* Arow = A + ((size_t)b * NPTS + p) * DFEAT;
        for (int og = 0; og < C1; og += 4) {
            const float4 av = *(const float4*)(Arow + og);
#pragma unroll
            for (int u = 0; u < 4; ++u) {
                const int o = og + u;
                const float avu = (u == 0) ? av.x : (u == 1) ? av.y
                                 : (u == 2) ? av.z : av.w;
                const float* wr = w0 + o * CIN;
                float acc = fmaf(wr[0], gx,
                            fmaf(wr[1], gy, fmaf(wr[2], gz, avu)));
                float sc = g0[o] * rsqrtf(rv0[o] + BN_EPS);
                float y = fmaf(sc, acc + b0[o] - rm0[o], bt0[o]);
                ylds[o][t] = fmaxf(y, 0.f);
            }
        }
    } else {
        float x[CIN];
        x[0] = gx; x[1] = gy; x[2] = gz;
        const float* pb = pts + (size_t)b * DFEAT * NPTS + p;
#pragma unroll
        for (int c = 0; c < DFEAT; ++c) x[3 + c] = pb[(size_t)c * NPTS];
        for (int o = 0; o < C1; ++o) {
            const float* wr = w0 + o * CIN;
            float a0 = 0.f, a1 = 0.f, a2 = 0.f, a3 = 0.f;
#pragma unroll
            for (int c = 0; c < 64; c += 4) {
                a0 = fmaf(wr[c], x[c], a0);
                a1 = fmaf(wr[c + 1], x[c + 1], a1);
                a2 = fmaf(wr[c + 2], x[c + 2], a2);
                a3 = fmaf(wr[c + 3], x[c + 3], a3);
            }
            a0 = fmaf(wr[64], x[64], a0);
            a1 = fmaf(wr[65], x[65], a1);
            a2 = fmaf(wr[66], x[66], a2);
            float acc = (a0 + a1) + (a2 + a3);
            float sc = g0[o] * rsqrtf(rv0[o] + BN_EPS);
            float y = fmaf(sc, acc + b0[o] - rm0[o], bt0[o]);
            ylds[o][t] = fmaxf(y, 0.f);
        }
    }
    __syncthreads();
    float x1[C1];
#pragma unroll
    for (int c = 0; c < C1; ++c) x1[c] = ylds[c][t];
    __syncthreads();

    // layer 2: 64 -> 64
    for (int o = 0; o < C2; ++o) {
        const float* wr = w1 + o * C1;
        float a0 = 0.f, a1 = 0.f, a2 = 0.f, a3 = 0.f;
#pragma unroll
        for (int c = 0; c < C1; c += 4) {
            a0 = fmaf(wr[c], x1[c], a0);
            a1 = fmaf(wr[c + 1], x1[c + 1], a1);
            a2 = fmaf(wr[c + 2], x1[c + 2], a2);
            a3 = fmaf(wr[c + 3], x1[c + 3], a3);
        }
        float acc = (a0 + a1) + (a2 + a3);
        float sc = g1[o] * rsqrtf(rv1[o] + BN_EPS);
        float y = fmaf(sc, acc + b1[o] - rm1[o], bt1[o]);
        ylds[o][t] = fmaxf(y, 0.f);
    }
    __syncthreads();
    float x2[C2];
#pragma unroll
    for (int c = 0; c < C2; ++c) x2[c] = ylds[c][t];

    // layer 3: 64 -> 128; k-max BEFORE BN+ReLU (monotone, sign-safe), DPP
    // reduce on the VALU pipe, writer lane k == 31.
    float* ob = outf + (size_t)b * C3 * NPOINT;
    for (int o = 0; o < C3; ++o) {
        const float* wr = w2 + o * C2;
        float a0 = 0.f, a1 = 0.f, a2 = 0.f, a3 = 0.f;
#pragma unroll
        for (int c = 0; c < C2; c += 4) {
            a0 = fmaf(wr[c], x2[c], a0);
            a1 = fmaf(wr[c + 1], x2[c + 1], a1);
            a2 = fmaf(wr[c + 2], x2[c + 2], a2);
            a3 = fmaf(wr[c + 3], x2[c + 3], a3);
        }
        float acc = (a0 + a1) + (a2 + a3);
        float sc = g2[o] * rsqrtf(rv2[o] + BN_EPS);
        float key = (sc >= 0.f) ? acc : -acc;
        float mred = max32_lane31(key);
        if (k == 31) {
            float asel = (sc >= 0.f) ? mred : -mred;
            float y = fmaf(sc, asel + b2[o] - rm2[o], bt2[o]);
            ob[(size_t)o * NPOINT + s] = fmaxf(y, 0.f);
        }
    }
}

// ---------------------------------------------------------------------------
extern "C" void kernel_launch(void* const* d_in, const int* in_sizes, int n_in,
                              void* d_out, int out_size, void* d_ws, size_t ws_size,
                              hipStream_t stream) {
    const float* xyz = (const float*)d_in[0];
    const float* pts = (const float*)d_in[1];
    const float* w0 = (const float*)d_in[2];
    const float* b0 = (const float*)d_in[3];
    const float* g0 = (const float*)d_in[4];
    const float* bt0 = (const float*)d_in[5];
    const float* rm0 = (const float*)d_in[6];
    const float* rv0 = (const float*)d_in[7];
    const float* w1 = (const float*)d_in[8];
    const float* b1 = (const float*)d_in[9];
    const float* g1 = (const float*)d_in[10];
    const float* bt1 = (const float*)d_in[11];
    const float* rm1 = (const float*)d_in[12];
    const float* rv1 = (const float*)d_in[13];
    const float* w2 = (const float*)d_in[14];
    const float* b2 = (const float*)d_in[15];
    const float* g2 = (const float*)d_in[16];
    const float* bt2 = (const float*)d_in[17];
    const float* rm2 = (const float*)d_in[18];
    const float* rv2 = (const float*)d_in[19];

    float* out = (float*)d_out;
    float* outf = out + (size_t)BATCH * 3 * NPOINT;

    const size_t idx_bytes = (size_t)BATCH * NPOINT * NSAMPLE * sizeof(int);  // 1 MB
    const size_t idx_pad = (idx_bytes + 255) & ~(size_t)255;
    const size_t A_bytes = (size_t)BATCH * NPTS * DFEAT * sizeof(float);      // 8 MB
    int* idx = (int*)d_ws;
    float* A = (float*)((char*)d_ws + idx_pad);
    const bool useA = ws_size >= idx_pad + A_bytes;

    fps_kernel<<<BATCH, 512, 0, stream>>>(xyz, out);
    if (useA) layer1_pts_kernel<<<BATCH * 64, 256, 0, stream>>>(pts, w0, A);
    ballquery_kernel<<<BATCH * NPOINT / 4, 256, 0, stream>>>(xyz, out, idx);
    if (useA) {
        mlp_kernel<1><<<BATCH * NPOINT / 8, 256, 0, stream>>>(
            xyz, pts, A, idx, out, w0, b0, g0, bt0, rm0, rv0, w1, b1, g1, bt1,
            rm1, rv1, w2, b2, g2, bt2, rm2, rv2, outf);
    } else {
        mlp_kernel<0><<<BATCH * NPOINT / 8, 256, 0, stream>>>(
            xyz, pts, A, idx, out, w0, b0, g0, bt0, rm0, rv0, w1, b1, g1, bt1,
            rm1, rv1, w2, b2, g2, bt2, rm2, rv2, outf);
    }
}